// Round 17
// baseline (124.545 us; speedup 1.0000x reference)
//
#include <hip/hip_runtime.h>

#define HW 64
#define NB 4
#define CH 256

typedef __attribute__((address_space(1))) const void* gptr_t;
typedef __attribute__((address_space(3))) void* lptr_t;
typedef __attribute__((ext_vector_type(8))) short bf8v;   // 8 bf16 bit-patterns
typedef __attribute__((ext_vector_type(4))) float f32x4;

__device__ __forceinline__ void gll16(const void* g, void* l) {
  __builtin_amdgcn_global_load_lds((gptr_t)g, (lptr_t)l, 16, 0, 0);
}
__device__ __forceinline__ ushort f2b(float f) {
  union { float f; uint u; } v; v.f = f;
  uint r = v.u + 0x7FFF + ((v.u >> 16) & 1);
  return (ushort)(r >> 16);
}
__device__ __forceinline__ uint cvt_pk_bf16(float lo, float hi) {
  uint r;
  asm("v_cvt_pk_bf16_f32 %0, %1, %2" : "=v"(r) : "v"(lo), "v"(hi));
  return r;
}
__device__ __forceinline__ float asf(uint u) {
  union { uint u; float f; } v; v.u = u; return v.f;
}

// bilinear-combine 4 corner chunks (8 bf16 each) with weights gw -> 8 bf16 out
__device__ __forceinline__ void combine_store(
    const uint4& c0, const uint4& c1, const uint4& c2, const uint4& c3,
    const float4& gw, ushort* dst)
{
  uint o[4];
  const uint* p0 = (const uint*)&c0; const uint* p1 = (const uint*)&c1;
  const uint* p2 = (const uint*)&c2; const uint* p3 = (const uint*)&c3;
  #pragma unroll
  for (int w = 0; w < 4; ++w) {
    const float lo = gw.x * asf(p0[w] << 16) + gw.y * asf(p1[w] << 16)
                   + gw.z * asf(p2[w] << 16) + gw.w * asf(p3[w] << 16);
    const float hi = gw.x * asf(p0[w] & 0xffff0000u) + gw.y * asf(p1[w] & 0xffff0000u)
                   + gw.z * asf(p2[w] & 0xffff0000u) + gw.w * asf(p3[w] & 0xffff0000u);
    o[w] = cvt_pk_bf16(lo, hi);
  }
  uint4 r; r.x = o[0]; r.y = o[1]; r.z = o[2]; r.w = o[3];
  *(uint4*)dst = r;
}

// ---------------------------------------------------------------------------
// prep_k: fused pack_x + pack_w + zero_borders (round-14 version, unchanged).
// ---------------------------------------------------------------------------
__global__ __launch_bounds__(256) void prep_k(
    const float* __restrict__ x,
    const float* __restrict__ w1, const float* __restrict__ w2,
    const float* __restrict__ dw, const float* __restrict__ pw,
    const float* __restrict__ pb,
    ushort* __restrict__ xpad, ushort* __restrict__ res1, ushort* __restrict__ res2,
    ushort* __restrict__ wpk1, ushort* __restrict__ wpk2,
    ushort* __restrict__ dwpk, ushort* __restrict__ wpkO, float* __restrict__ pbias)
{
  __shared__ float tile[64][261];
  const int bid = blockIdx.x, t = threadIdx.x;

  if (bid < 256) {
    const int b = bid >> 6, i = bid & 63;
    const int wave = t >> 6, l = t & 63;
    const float* src = x + (size_t)b * CH * 4096 + (size_t)i * 64;
    for (int cc = 0; cc < 64; ++cc) {
      const int c = cc * 4 + wave;
      tile[l][c] = src[(size_t)c * 4096 + l];
    }
    __syncthreads();
    const int c0 = (t & 31) * 8;
    #pragma unroll
    for (int jj = 0; jj < 8; ++jj) {
      const int j = (t >> 5) + jj * 8;
      const float4 v0 = *(const float4*)&tile[j][c0];
      const float4 v1 = *(const float4*)&tile[j][c0 + 4];
      uint4 o;
      o.x = cvt_pk_bf16(v0.x, v0.y);
      o.y = cvt_pk_bf16(v0.z, v0.w);
      o.z = cvt_pk_bf16(v1.x, v1.y);
      o.w = cvt_pk_bf16(v1.z, v1.w);
      *(uint4*)&xpad[((size_t)b * 4356 + (i + 1) * 66 + (j + 1)) * 256 + c0] = o;
    }
  } else if (bid < 1156) {
    const int id = (bid - 256) * 256 + t;
    if (id < 3 * 73728) {
      const int tsel = id / 73728, r = id % 73728;
      const int kc = r & 3, o = (r >> 2) & 255, ct = r >> 10;
      const int cb = ct / 9, tap = ct % 9;
      const float* w = (tsel == 0) ? w1 : (tsel == 1) ? w2 : dw;
      const float* s = w + ((size_t)o * CH + cb * 32 + kc * 8) * 9 + tap;
      ushort* d = ((tsel == 0) ? wpk1 : (tsel == 1) ? wpk2 : dwpk) + (size_t)r * 8;
      #pragma unroll
      for (int j = 0; j < 8; ++j) d[j] = f2b(s[j * 9]);
    } else if (id < 3 * 73728 + 9216) {
      const int r = id - 3 * 73728;
      const int kc = r & 3, o = (r >> 2) & 31, ct = r >> 7;
      const int cb = ct / 9, tap = ct % 9;
      ushort* d = wpkO + (size_t)r * 8;
      if (o < 18) {
        const float* s = pw + ((size_t)o * CH + cb * 32 + kc * 8) * 9 + tap;
        #pragma unroll
        for (int j = 0; j < 8; ++j) d[j] = f2b(s[j * 9]);
      } else {
        #pragma unroll
        for (int j = 0; j < 8; ++j) d[j] = 0;
      }
    }
    if (id < 32) pbias[id] = (id < 18) ? pb[id] : 0.f;
  } else {
    const int v = bid - 1156;
    const int buf = v >> 2, b = v & 3;
    ushort* base = (buf == 0 ? xpad : buf == 1 ? res1 : res2) + (size_t)b * 4356 * 256;
    uint4 z; z.x = 0; z.y = 0; z.z = 0; z.w = 0;
    for (int u = t; u < 260 * 32; u += 256) {
      const int p = u >> 5, k = u & 31;
      int r, cc;
      if (p < 66)       { r = 0;       cc = p; }
      else if (p < 132) { r = 65;      cc = p - 66; }
      else if (p < 196) { r = p - 131; cc = 0; }
      else              { r = p - 195; cc = 65; }
      *(uint4*)&base[((size_t)r * 66 + cc) * 256 + k * 8] = z;
    }
  }
}

// ---------------------------------------------------------------------------
// Implicit-GEMM 3x3 conv via MFMA. OTOT=256: FULL-ROW block — 512 thr = 8
// waves (each o-32 slice, FO=2, FP=4 full row), grid 256 = (b,i). Patch
// staged ONCE per row (L2 staging halved vs 2-half-block r12); STAGE issued
// between weight ping-pong sets so prefetch gets ~2 chunk-phases of MFMA
// cover and the loop-top barrier finds vmcnt drained. OTOT=32: 256 thr,
// 4 waves (px quarters), FO=2/FP=1 (unchanged r12 structure).
// ---------------------------------------------------------------------------
template<int OTOT, int OUTMODE>
__global__ __launch_bounds__(512, 2) void conv_mfma(
    const ushort* __restrict__ apad, const ushort* __restrict__ wpk,
    const float* __restrict__ bias, const float* __restrict__ xres,
    void* __restrict__ outp)
{
  constexpr int NT = (OTOT == 256) ? 512 : 256;
  __shared__ __align__(16) ushort patch[2][6336];
  const int t = threadIdx.x, wave = t >> 6, l = t & 63;
  const int b = (blockIdx.x & 255) >> 6, i = blockIdx.x & 63;
  const int ln = l & 15, kc8 = (l >> 4) * 8;

  constexpr int FO = 2;
  constexpr int FP = (OTOT == 256) ? 4 : 1;
  const int oS  = (OTOT == 256) ? (wave * 32) : 0;
  const int pxB = (OTOT == 256) ? 0 : (wave * 16);

  const ushort* rowbase = apad + ((size_t)(b * 66 + i) * 66) * 256;

  f32x4 acc[FO][FP];
  #pragma unroll
  for (int a = 0; a < FO; ++a)
    #pragma unroll
    for (int d = 0; d < FP; ++d) acc[a][d] = (f32x4){0.f, 0.f, 0.f, 0.f};

  // 792 16B-chunks; LDS dest linear, global source pre-swizzled by ((p>>1)&3)
  #define STAGE(buf, cb)                                                        \
    _Pragma("unroll")                                                           \
    for (int it = 0; it < ((NT == 512) ? 2 : 4); ++it) {                        \
      const int e = t + it * NT;                                                \
      if (e < 792) {                                                            \
        const int r = e / 264, u = e - r * 264;                                 \
        const int p = r * 66 + (u >> 2);                                        \
        const int sl = (u & 3) ^ ((p >> 1) & 3);                                \
        const ushort* s = rowbase + (size_t)p * 256 + (cb) * 32 + sl * 8;       \
        gll16(s, (ushort*)&patch[buf][0] + (size_t)e * 8);                      \
      }                                                                         \
    }

  #define LOADW(dst, cb_, ch_)                                                  \
    _Pragma("unroll")                                                           \
    for (int q = 0; q < 3; ++q) {                                               \
      _Pragma("unroll")                                                         \
      for (int fo = 0; fo < FO; ++fo)                                           \
        dst[q][fo] = *(const bf8v*)&wpk[((size_t)(((cb_) * 9 + (ch_) * 3 + q) * OTOT) + oS + fo * 16 + ln) * 32 + kc8]; \
    }

  #define MFMACH(ch_, wset) {                                                   \
      __builtin_amdgcn_s_setprio(1);                                            \
      _Pragma("unroll")                                                         \
      for (int q = 0; q < 3; ++q) {                                             \
        const int tap = (ch_) * 3 + q;                                          \
        const int ky = tap / 3, kx = tap % 3;                                   \
        _Pragma("unroll")                                                       \
        for (int fp = 0; fp < FP; ++fp) {                                       \
          const int px = pxB + fp * 16 + ln;                                    \
          const int pix = ky * 66 + px + kx;                                    \
          const int sl = (l >> 4) ^ ((pix >> 1) & 3);                           \
          const bf8v pf = *(const bf8v*)&pbuf[pix * 32 + sl * 8];               \
          _Pragma("unroll")                                                     \
          for (int fo = 0; fo < FO; ++fo)                                       \
            acc[fo][fp] = __builtin_amdgcn_mfma_f32_16x16x32_bf16(wset[q][fo], pf, acc[fo][fp], 0, 0, 0); \
        }                                                                       \
      }                                                                         \
      __builtin_amdgcn_s_setprio(0);                                            \
    }

  STAGE(0, 0)
  for (int cb = 0; cb < 8; ++cb) {
    __syncthreads();                           // patch[cb&1] ready
    const ushort* pbuf = &patch[cb & 1][0];
    bf8v wA[3][FO], wB[3][FO];
    LOADW(wA, cb, 0)                           // oldest vmcnt entries
    if (cb < 7) { STAGE((cb + 1) & 1, cb + 1) }  // covered by ch0+ch1 phases
    LOADW(wB, cb, 1)
    MFMACH(0, wA)                              // waits wA only (oldest)
    LOADW(wA, cb, 2)
    MFMACH(1, wB)                              // drains STAGE (long complete)
    MFMACH(2, wA)
  }
  #undef MFMACH
  #undef LOADW
  #undef STAGE

  #pragma unroll
  for (int fo = 0; fo < FO; ++fo) {
    #pragma unroll
    for (int fp = 0; fp < FP; ++fp) {
      const f32x4 a = acc[fo][fp];
      const int o = oS + fo * 16 + (l >> 4) * 4;
      const int j = pxB + fp * 16 + ln;
      const float4 bv = *(const float4*)&bias[o];
      float v0 = a[0] + bv.x, v1 = a[1] + bv.y, v2 = a[2] + bv.z, v3 = a[3] + bv.w;
      if (OUTMODE == 0) {
        const size_t xb = (((size_t)b * CH + o) * HW + i) * HW + j;
        v0 = fmaxf(v0, 0.f) + xres[xb];
        v1 = fmaxf(v1, 0.f) + xres[xb + 4096];
        v2 = fmaxf(v2, 0.f) + xres[xb + 8192];
        v3 = fmaxf(v3, 0.f) + xres[xb + 12288];
      }
      if (OUTMODE == 2) {
        float* op = (float*)outp + ((size_t)b * 4096 + i * 64 + j) * 32 + o;
        float4 r; r.x = v0; r.y = v1; r.z = v2; r.w = v3;
        *(float4*)op = r;
      } else {
        ushort* op = (ushort*)outp + ((size_t)b * 4356 + (i + 1) * 66 + (j + 1)) * 256 + o;
        ushort4 s; s.x = f2b(v0); s.y = f2b(v1); s.z = f2b(v2); s.w = f2b(v3);
        *(ushort4*)op = s;
      }
    }
  }
}

// ---------------------------------------------------------------------------
// Deform GEMM + residual — ROUND-12 VERSION VERBATIM (best measured: 44.1us).
// ---------------------------------------------------------------------------
__global__ __launch_bounds__(512, 2) void deform_mfma(
    const ushort* __restrict__ res2pad, const float* __restrict__ offs,
    const ushort* __restrict__ dwpk, const float* __restrict__ x,
    float* __restrict__ out)
{
  __shared__ __align__(16) ushort samp[2][18432];   // 2 x 36864 B
  __shared__ __align__(16) int    tblI[576 * 4];
  __shared__ __align__(16) float  tblW[576 * 4];

  const int t = threadIdx.x, wave = t >> 6, l = t & 63;
  const int blk = (blockIdx.x & 7) * 32 + (blockIdx.x >> 3);   // XCD swizzle
  const int b = blk >> 6, i = blk & 63;
  const int ln = l & 15, kc8 = (l >> 4) * 8;
  const int oS = wave * 32;

  #pragma unroll
  for (int k2 = 0; k2 < 2; ++k2) {
    const int e = t + k2 * 512;
    if (e < 576) {
      const int n = e >> 6, j = e & 63;
      const int ki = n / 3, kj = n % 3;
      const float offr = offs[((size_t)(b * 64 + i) * 64 + j) * 32 + n];
      const float offc = offs[((size_t)(b * 64 + i) * 64 + j) * 32 + 9 + n];
      const float prow = offr + (float)(ki - 1) + (float)(i + 1);
      const float pcol = offc + (float)(kj - 1) + (float)(j + 1);
      const float fx = floorf(prow), fy = floorf(pcol);
      const float qlx = fminf(fmaxf(fx, 0.f), 65.f);
      const float qly = fminf(fmaxf(fy, 0.f), 65.f);
      const float qrx = fminf(fmaxf(fx + 1.f, 0.f), 65.f);
      const float qry = fminf(fmaxf(fy + 1.f, 0.f), 65.f);
      const float pr  = fminf(fmaxf(prow, 0.f), 65.f);
      const float pc  = fminf(fmaxf(pcol, 0.f), 65.f);
      tblI[e * 4 + 0] = ((int)qlx * 66 + (int)qly) * 512;   // byte offsets
      tblI[e * 4 + 1] = ((int)qrx * 66 + (int)qry) * 512;
      tblI[e * 4 + 2] = ((int)qlx * 66 + (int)qry) * 512;
      tblI[e * 4 + 3] = ((int)qrx * 66 + (int)qly) * 512;
      tblW[e * 4 + 0] = (1.f + qlx - pr) * (1.f + qly - pc);
      tblW[e * 4 + 1] = (1.f - qrx + pr) * (1.f - qry + pc);
      tblW[e * 4 + 2] = (1.f + qlx - pr) * (1.f - qry + pc);
      tblW[e * 4 + 3] = (1.f - qrx + pr) * (1.f + qly - pc);
    }
  }

  f32x4 acc[2][4];
  #pragma unroll
  for (int a = 0; a < 2; ++a)
    #pragma unroll
    for (int d = 0; d < 4; ++d) acc[a][d] = (f32x4){0.f, 0.f, 0.f, 0.f};

  const char* res2b = (const char*)(res2pad + (size_t)b * 4356 * 256);

  #define SAMPLE_CB(cb_, buf_)                                                  \
    _Pragma("unroll")                                                           \
    for (int k = 0; k < 5; ++k) {                                               \
      if (k < 4 || t < 256) {                                                   \
        const int u = t + k * 512;                                              \
        const int e = u >> 2, i16 = u & 3;                                      \
        const int4 iv = *(const int4*)&tblI[e * 4];                             \
        const float4 gw = *(const float4*)&tblW[e * 4];                         \
        const char* gb = res2b + (cb_) * 64 + i16 * 16;                         \
        const uint4 c0 = *(const uint4*)(gb + iv.x);                            \
        const uint4 c1 = *(const uint4*)(gb + iv.y);                            \
        const uint4 c2 = *(const uint4*)(gb + iv.z);                            \
        const uint4 c3 = *(const uint4*)(gb + iv.w);                            \
        const int sl = i16 ^ ((e >> 1) & 3);                                    \
        combine_store(c0, c1, c2, c3, gw, &samp[buf_][(size_t)e * 32 + sl * 8]);\
      }                                                                         \
    }

  __syncthreads();          // table ready
  SAMPLE_CB(0, 0)
  __syncthreads();

  const int rsl = ((l >> 4) ^ ((ln >> 1) & 3)) * 8;   // read-slot swizzle

  for (int cb = 0; cb < 8; ++cb) {
    const ushort* sb = &samp[cb & 1][0];
    const ushort* wbase = dwpk + (size_t)(cb * 9) * 256 * 32;

    #pragma unroll
    for (int ch = 0; ch < 3; ++ch) {
      bf8v bfr[3][2];
      #pragma unroll
      for (int q = 0; q < 3; ++q)
        #pragma unroll
        for (int fo = 0; fo < 2; ++fo)
          bfr[q][fo] = *(const bf8v*)&wbase[((size_t)((ch * 3 + q) * 256) + oS + fo * 16 + ln) * 32 + kc8];
      __builtin_amdgcn_s_setprio(1);
      #pragma unroll
      for (int q = 0; q < 3; ++q) {
        const int tap = ch * 3 + q;
        #pragma unroll
        for (int fp = 0; fp < 4; ++fp) {
          const bf8v af = *(const bf8v*)&sb[(tap * 64 + fp * 16 + ln) * 32 + rsl];
          #pragma unroll
          for (int fo = 0; fo < 2; ++fo)
            acc[fo][fp] = __builtin_amdgcn_mfma_f32_16x16x32_bf16(af, bfr[q][fo], acc[fo][fp], 0, 0, 0);
        }
      }
      __builtin_amdgcn_s_setprio(0);
    }

    if (cb < 7) { SAMPLE_CB(cb + 1, (cb + 1) & 1) }
    __syncthreads();
  }
  #undef SAMPLE_CB

  #pragma unroll
  for (int fo = 0; fo < 2; ++fo) {
    #pragma unroll
    for (int fp = 0; fp < 4; ++fp) {
      const f32x4 a = acc[fo][fp];
      const int o = oS + fo * 16 + ln;
      const int j0 = fp * 16 + (l >> 4) * 4;
      const size_t base = (((size_t)b * CH + o) * HW + i) * HW + j0;
      const float4 xv = *(const float4*)&x[base];
      float4 r; r.x = a[0] + xv.x; r.y = a[1] + xv.y; r.z = a[2] + xv.z; r.w = a[3] + xv.w;
      *(float4*)&out[base] = r;
    }
  }
}

// ---------------------------------------------------------------------------
extern "C" void kernel_launch(void* const* d_in, const int* in_sizes, int n_in,
                              void* d_out, int out_size, void* d_ws, size_t ws_size,
                              hipStream_t stream) {
  (void)in_sizes; (void)n_in; (void)out_size; (void)ws_size;
  const float* x  = (const float*)d_in[0];
  const float* w1 = (const float*)d_in[1];
  const float* b1 = (const float*)d_in[2];
  const float* w2 = (const float*)d_in[3];
  const float* b2 = (const float*)d_in[4];
  const float* pw = (const float*)d_in[5];
  const float* pb = (const float*)d_in[6];
  const float* dw = (const float*)d_in[7];
  float* out = (float*)d_out;

  char* w = (char*)d_ws;
  size_t off = 0;
  auto carve = [&](size_t bytes) { char* p = w + off; off += (bytes + 255) & ~(size_t)255; return p; };
  ushort* xpad  = (ushort*)carve(8929280);
  ushort* res1  = (ushort*)carve(8929280);
  ushort* res2  = (ushort*)carve(8929280);
  ushort* wpk1  = (ushort*)carve(1179648);
  ushort* wpk2  = (ushort*)carve(1179648);
  ushort* wpkO  = (ushort*)carve(147456);
  ushort* dwpk  = (ushort*)carve(1179648);
  float*  pbias = (float*) carve(256);
  float*  offs  = (float*) carve(2097152);

  prep_k<<<1168, 256, 0, stream>>>(x, w1, w2, dw, pw, pb,
                                   xpad, res1, res2, wpk1, wpk2, dwpk, wpkO, pbias);
  conv_mfma<256, 0><<<256, 512, 0, stream>>>(xpad, wpk1, b1, x, res1);
  conv_mfma<256, 1><<<256, 512, 0, stream>>>(res1, wpk2, b2, nullptr, res2);
  conv_mfma<32, 2><<<256, 256, 0, stream>>>(res2, wpkO, pbias, nullptr, offs);
  deform_mfma<<<NB * HW, 512, 0, stream>>>(res2, offs, dwpk, x, out);
}

// Round 18
// 121.962 us; speedup vs baseline: 1.0212x; 1.0212x over previous
//
#include <hip/hip_runtime.h>

#define HW 64
#define NB 4
#define CH 256

typedef __attribute__((address_space(1))) const void* gptr_t;
typedef __attribute__((address_space(3))) void* lptr_t;
typedef __attribute__((ext_vector_type(8))) short bf8v;   // 8 bf16 bit-patterns
typedef __attribute__((ext_vector_type(4))) float f32x4;

__device__ __forceinline__ void gll16(const void* g, void* l) {
  __builtin_amdgcn_global_load_lds((gptr_t)g, (lptr_t)l, 16, 0, 0);
}
__device__ __forceinline__ ushort f2b(float f) {
  union { float f; uint u; } v; v.f = f;
  uint r = v.u + 0x7FFF + ((v.u >> 16) & 1);
  return (ushort)(r >> 16);
}
__device__ __forceinline__ uint cvt_pk_bf16(float lo, float hi) {
  uint r;
  asm("v_cvt_pk_bf16_f32 %0, %1, %2" : "=v"(r) : "v"(lo), "v"(hi));
  return r;
}
__device__ __forceinline__ float asf(uint u) {
  union { uint u; float f; } v; v.u = u; return v.f;
}

// bilinear-combine 4 corner chunks (8 bf16 each) with weights gw -> 8 bf16 out
__device__ __forceinline__ void combine_store(
    const uint4& c0, const uint4& c1, const uint4& c2, const uint4& c3,
    const float4& gw, ushort* dst)
{
  uint o[4];
  const uint* p0 = (const uint*)&c0; const uint* p1 = (const uint*)&c1;
  const uint* p2 = (const uint*)&c2; const uint* p3 = (const uint*)&c3;
  #pragma unroll
  for (int w = 0; w < 4; ++w) {
    const float lo = gw.x * asf(p0[w] << 16) + gw.y * asf(p1[w] << 16)
                   + gw.z * asf(p2[w] << 16) + gw.w * asf(p3[w] << 16);
    const float hi = gw.x * asf(p0[w] & 0xffff0000u) + gw.y * asf(p1[w] & 0xffff0000u)
                   + gw.z * asf(p2[w] & 0xffff0000u) + gw.w * asf(p3[w] & 0xffff0000u);
    o[w] = cvt_pk_bf16(lo, hi);
  }
  uint4 r; r.x = o[0]; r.y = o[1]; r.z = o[2]; r.w = o[3];
  *(uint4*)dst = r;
}

// ---------------------------------------------------------------------------
// prep_k: fused pack_x + pack_w + zero_borders (3 launches -> 1).
// blocks [0,256): pack_x (b,i); [256,1156): pack_w; [1156,1168): borders.
// ---------------------------------------------------------------------------
__global__ __launch_bounds__(256) void prep_k(
    const float* __restrict__ x,
    const float* __restrict__ w1, const float* __restrict__ w2,
    const float* __restrict__ dw, const float* __restrict__ pw,
    const float* __restrict__ pb,
    ushort* __restrict__ xpad, ushort* __restrict__ res1, ushort* __restrict__ res2,
    ushort* __restrict__ wpk1, ushort* __restrict__ wpk2,
    ushort* __restrict__ dwpk, ushort* __restrict__ wpkO, float* __restrict__ pbias)
{
  __shared__ float tile[64][261];
  const int bid = blockIdx.x, t = threadIdx.x;

  if (bid < 256) {
    // ---- pack_x: x NCHW f32 -> xpad [4][66][66][256] bf16 interior ----
    const int b = bid >> 6, i = bid & 63;
    const int wave = t >> 6, l = t & 63;
    const float* src = x + (size_t)b * CH * 4096 + (size_t)i * 64;
    for (int cc = 0; cc < 64; ++cc) {
      const int c = cc * 4 + wave;
      tile[l][c] = src[(size_t)c * 4096 + l];
    }
    __syncthreads();
    const int c0 = (t & 31) * 8;
    #pragma unroll
    for (int jj = 0; jj < 8; ++jj) {
      const int j = (t >> 5) + jj * 8;
      const float4 v0 = *(const float4*)&tile[j][c0];
      const float4 v1 = *(const float4*)&tile[j][c0 + 4];
      uint4 o;
      o.x = cvt_pk_bf16(v0.x, v0.y);
      o.y = cvt_pk_bf16(v0.z, v0.w);
      o.z = cvt_pk_bf16(v1.x, v1.y);
      o.w = cvt_pk_bf16(v1.z, v1.w);
      *(uint4*)&xpad[((size_t)b * 4356 + (i + 1) * 66 + (j + 1)) * 256 + c0] = o;
    }
  } else if (bid < 1156) {
    // ---- pack_w ----
    const int id = (bid - 256) * 256 + t;
    if (id < 3 * 73728) {
      const int tsel = id / 73728, r = id % 73728;
      const int kc = r & 3, o = (r >> 2) & 255, ct = r >> 10;
      const int cb = ct / 9, tap = ct % 9;
      const float* w = (tsel == 0) ? w1 : (tsel == 1) ? w2 : dw;
      const float* s = w + ((size_t)o * CH + cb * 32 + kc * 8) * 9 + tap;
      ushort* d = ((tsel == 0) ? wpk1 : (tsel == 1) ? wpk2 : dwpk) + (size_t)r * 8;
      #pragma unroll
      for (int j = 0; j < 8; ++j) d[j] = f2b(s[j * 9]);
    } else if (id < 3 * 73728 + 9216) {
      const int r = id - 3 * 73728;
      const int kc = r & 3, o = (r >> 2) & 31, ct = r >> 7;
      const int cb = ct / 9, tap = ct % 9;
      ushort* d = wpkO + (size_t)r * 8;
      if (o < 18) {
        const float* s = pw + ((size_t)o * CH + cb * 32 + kc * 8) * 9 + tap;
        #pragma unroll
        for (int j = 0; j < 8; ++j) d[j] = f2b(s[j * 9]);
      } else {
        #pragma unroll
        for (int j = 0; j < 8; ++j) d[j] = 0;
      }
    }
    if (id < 32) pbias[id] = (id < 18) ? pb[id] : 0.f;
  } else {
    // ---- zero borders: 260 border pixels x 256 ch per (buf, b) ----
    const int v = bid - 1156;
    const int buf = v >> 2, b = v & 3;
    ushort* base = (buf == 0 ? xpad : buf == 1 ? res1 : res2) + (size_t)b * 4356 * 256;
    uint4 z; z.x = 0; z.y = 0; z.z = 0; z.w = 0;
    for (int u = t; u < 260 * 32; u += 256) {
      const int p = u >> 5, k = u & 31;
      int r, cc;
      if (p < 66)       { r = 0;       cc = p; }
      else if (p < 132) { r = 65;      cc = p - 66; }
      else if (p < 196) { r = p - 131; cc = 0; }
      else              { r = p - 195; cc = 65; }
      *(uint4*)&base[((size_t)r * 66 + cc) * 256 + k * 8] = z;
    }
  }
}

// ---------------------------------------------------------------------------
// Implicit-GEMM 3x3 conv via MFMA — round-12/14 version (best measured).
// FO=2, grid 512 = (b,i) x o-half, 2 blocks/CU co-resident.
// ---------------------------------------------------------------------------
template<int OTOT, int OUTMODE>
__global__ __launch_bounds__(256, 2) void conv_mfma(
    const ushort* __restrict__ apad, const ushort* __restrict__ wpk,
    const float* __restrict__ bias, const float* __restrict__ xres,
    void* __restrict__ outp)
{
  __shared__ __align__(16) ushort patch[2][6336];
  const int t = threadIdx.x, wave = t >> 6, l = t & 63;
  const int ot  = (OTOT == 256) ? (blockIdx.x >> 8) : 0;
  const int rem = blockIdx.x & 255;
  const int b = rem >> 6, i = rem & 63;
  const int ln = l & 15, kc8 = (l >> 4) * 8;

  constexpr int FO = 2;
  constexpr int FP = (OTOT == 256) ? 4 : 1;
  const int oS  = (OTOT == 256) ? (ot * 128 + wave * 32) : 0;
  const int pxB = (OTOT == 256) ? 0 : (wave * 16);

  const ushort* rowbase = apad + ((size_t)(b * 66 + i) * 66) * 256;

  f32x4 acc[FO][FP];
  #pragma unroll
  for (int a = 0; a < FO; ++a)
    #pragma unroll
    for (int d = 0; d < FP; ++d) acc[a][d] = (f32x4){0.f, 0.f, 0.f, 0.f};

  #define STAGE(buf, cb)                                                        \
    _Pragma("unroll")                                                           \
    for (int it = 0; it < 4; ++it) {                                            \
      const int e = t + it * 256;                                               \
      if (it < 3 || t < 24) {                                                   \
        const int r = e / 264, u = e - r * 264;                                 \
        const int p = r * 66 + (u >> 2);                                        \
        const int sl = (u & 3) ^ ((p >> 1) & 3);                                \
        const ushort* s = rowbase + (size_t)p * 256 + (cb) * 32 + sl * 8;       \
        gll16(s, (ushort*)&patch[buf][0] + (size_t)e * 8);                      \
      }                                                                         \
    }

  STAGE(0, 0)
  for (int cb = 0; cb < 8; ++cb) {
    __syncthreads();                           // patch[cb&1] ready
    const ushort* pbuf = &patch[cb & 1][0];
    #pragma unroll
    for (int ch = 0; ch < 3; ++ch) {
      bf8v wfr[3][FO];
      #pragma unroll
      for (int q = 0; q < 3; ++q) {
        const int tap = ch * 3 + q;
        #pragma unroll
        for (int fo = 0; fo < FO; ++fo)
          wfr[q][fo] = *(const bf8v*)&wpk[((size_t)((cb * 9 + tap) * OTOT) + oS + fo * 16 + ln) * 32 + kc8];
      }
      if (ch == 2 && cb < 7) { STAGE((cb + 1) & 1, cb + 1) }
      __builtin_amdgcn_s_setprio(1);
      #pragma unroll
      for (int q = 0; q < 3; ++q) {
        const int tap = ch * 3 + q;
        const int ky = tap / 3, kx = tap % 3;
        #pragma unroll
        for (int fp = 0; fp < FP; ++fp) {
          const int px = pxB + fp * 16 + ln;
          const int pix = ky * 66 + px + kx;
          const int sl = (l >> 4) ^ ((pix >> 1) & 3);
          const bf8v pf = *(const bf8v*)&pbuf[pix * 32 + sl * 8];
          #pragma unroll
          for (int fo = 0; fo < FO; ++fo)
            acc[fo][fp] = __builtin_amdgcn_mfma_f32_16x16x32_bf16(wfr[q][fo], pf, acc[fo][fp], 0, 0, 0);
        }
      }
      __builtin_amdgcn_s_setprio(0);
    }
  }
  #undef STAGE

  #pragma unroll
  for (int fo = 0; fo < FO; ++fo) {
    #pragma unroll
    for (int fp = 0; fp < FP; ++fp) {
      const f32x4 a = acc[fo][fp];
      const int o = oS + fo * 16 + (l >> 4) * 4;
      const int j = pxB + fp * 16 + ln;
      const float4 bv = *(const float4*)&bias[o];
      float v0 = a[0] + bv.x, v1 = a[1] + bv.y, v2 = a[2] + bv.z, v3 = a[3] + bv.w;
      if (OUTMODE == 0) {
        const size_t xb = (((size_t)b * CH + o) * HW + i) * HW + j;
        v0 = fmaxf(v0, 0.f) + xres[xb];
        v1 = fmaxf(v1, 0.f) + xres[xb + 4096];
        v2 = fmaxf(v2, 0.f) + xres[xb + 8192];
        v3 = fmaxf(v3, 0.f) + xres[xb + 12288];
      }
      if (OUTMODE == 2) {
        float* op = (float*)outp + ((size_t)b * 4096 + i * 64 + j) * 32 + o;
        float4 r; r.x = v0; r.y = v1; r.z = v2; r.w = v3;
        *(float4*)op = r;
      } else {
        ushort* op = (ushort*)outp + ((size_t)b * 4356 + (i + 1) * 66 + (j + 1)) * 256 + o;
        ushort4 s; s.x = f2b(v0); s.y = f2b(v1); s.z = f2b(v2); s.w = f2b(v3);
        *(ushort4*)op = s;
      }
    }
  }
}

// ---------------------------------------------------------------------------
// Deform GEMM + residual — ROUND-12 VERSION VERBATIM (best measured: 44.1us,
// VGPR 88, zero bank conflicts, no scratch). block=(b,i), 512 thr = 8 o-32
// waves, FO=2/FP=4, weights read once per block, samp dbuf, 1 barrier/cb.
// ---------------------------------------------------------------------------
__global__ __launch_bounds__(512, 2) void deform_mfma(
    const ushort* __restrict__ res2pad, const float* __restrict__ offs,
    const ushort* __restrict__ dwpk, const float* __restrict__ x,
    float* __restrict__ out)
{
  __shared__ __align__(16) ushort samp[2][18432];   // 2 x 36864 B
  __shared__ __align__(16) int    tblI[576 * 4];
  __shared__ __align__(16) float  tblW[576 * 4];

  const int t = threadIdx.x, wave = t >> 6, l = t & 63;
  const int blk = (blockIdx.x & 7) * 32 + (blockIdx.x >> 3);   // XCD swizzle
  const int b = blk >> 6, i = blk & 63;
  const int ln = l & 15, kc8 = (l >> 4) * 8;
  const int oS = wave * 32;

  // bilinear table: entries e = t (t<512) and 512+t (t<64)
  #pragma unroll
  for (int k2 = 0; k2 < 2; ++k2) {
    const int e = t + k2 * 512;
    if (e < 576) {
      const int n = e >> 6, j = e & 63;
      const int ki = n / 3, kj = n % 3;
      const float offr = offs[((size_t)(b * 64 + i) * 64 + j) * 32 + n];
      const float offc = offs[((size_t)(b * 64 + i) * 64 + j) * 32 + 9 + n];
      const float prow = offr + (float)(ki - 1) + (float)(i + 1);
      const float pcol = offc + (float)(kj - 1) + (float)(j + 1);
      const float fx = floorf(prow), fy = floorf(pcol);
      const float qlx = fminf(fmaxf(fx, 0.f), 65.f);
      const float qly = fminf(fmaxf(fy, 0.f), 65.f);
      const float qrx = fminf(fmaxf(fx + 1.f, 0.f), 65.f);
      const float qry = fminf(fmaxf(fy + 1.f, 0.f), 65.f);
      const float pr  = fminf(fmaxf(prow, 0.f), 65.f);
      const float pc  = fminf(fmaxf(pcol, 0.f), 65.f);
      tblI[e * 4 + 0] = ((int)qlx * 66 + (int)qly) * 512;   // byte offsets
      tblI[e * 4 + 1] = ((int)qrx * 66 + (int)qry) * 512;
      tblI[e * 4 + 2] = ((int)qlx * 66 + (int)qry) * 512;
      tblI[e * 4 + 3] = ((int)qrx * 66 + (int)qly) * 512;
      tblW[e * 4 + 0] = (1.f + qlx - pr) * (1.f + qly - pc);
      tblW[e * 4 + 1] = (1.f - qrx + pr) * (1.f - qry + pc);
      tblW[e * 4 + 2] = (1.f + qlx - pr) * (1.f - qry + pc);
      tblW[e * 4 + 3] = (1.f - qrx + pr) * (1.f + qly - pc);
    }
  }

  f32x4 acc[2][4];
  #pragma unroll
  for (int a = 0; a < 2; ++a)
    #pragma unroll
    for (int d = 0; d < 4; ++d) acc[a][d] = (f32x4){0.f, 0.f, 0.f, 0.f};

  const char* res2b = (const char*)(res2pad + (size_t)b * 4356 * 256);

  // sample channel-block cb into samp[buf]; units u = e*4+i16, e = tap*64+px
  // 2304 units over 512 threads (k=0..3 all, k=4 t<256). Swizzled store slot.
  #define SAMPLE_CB(cb_, buf_)                                                  \
    _Pragma("unroll")                                                           \
    for (int k = 0; k < 5; ++k) {                                               \
      if (k < 4 || t < 256) {                                                   \
        const int u = t + k * 512;                                              \
        const int e = u >> 2, i16 = u & 3;                                      \
        const int4 iv = *(const int4*)&tblI[e * 4];                             \
        const float4 gw = *(const float4*)&tblW[e * 4];                         \
        const char* gb = res2b + (cb_) * 64 + i16 * 16;                         \
        const uint4 c0 = *(const uint4*)(gb + iv.x);                            \
        const uint4 c1 = *(const uint4*)(gb + iv.y);                            \
        const uint4 c2 = *(const uint4*)(gb + iv.z);                            \
        const uint4 c3 = *(const uint4*)(gb + iv.w);                            \
        const int sl = i16 ^ ((e >> 1) & 3);                                    \
        combine_store(c0, c1, c2, c3, gw, &samp[buf_][(size_t)e * 32 + sl * 8]);\
      }                                                                         \
    }

  __syncthreads();          // table ready
  SAMPLE_CB(0, 0)
  __syncthreads();

  const int rsl = ((l >> 4) ^ ((ln >> 1) & 3)) * 8;   // read-slot swizzle

  for (int cb = 0; cb < 8; ++cb) {
    const ushort* sb = &samp[cb & 1][0];
    const ushort* wbase = dwpk + (size_t)(cb * 9) * 256 * 32;

    #pragma unroll
    for (int ch = 0; ch < 3; ++ch) {
      bf8v bfr[3][2];
      #pragma unroll
      for (int q = 0; q < 3; ++q)
        #pragma unroll
        for (int fo = 0; fo < 2; ++fo)
          bfr[q][fo] = *(const bf8v*)&wbase[((size_t)((ch * 3 + q) * 256) + oS + fo * 16 + ln) * 32 + kc8];
      __builtin_amdgcn_s_setprio(1);
      #pragma unroll
      for (int q = 0; q < 3; ++q) {
        const int tap = ch * 3 + q;
        #pragma unroll
        for (int fp = 0; fp < 4; ++fp) {
          const bf8v af = *(const bf8v*)&sb[(tap * 64 + fp * 16 + ln) * 32 + rsl];
          #pragma unroll
          for (int fo = 0; fo < 2; ++fo)
            acc[fo][fp] = __builtin_amdgcn_mfma_f32_16x16x32_bf16(af, bfr[q][fo], acc[fo][fp], 0, 0, 0);
        }
      }
      __builtin_amdgcn_s_setprio(0);
    }

    if (cb < 7) { SAMPLE_CB(cb + 1, (cb + 1) & 1) }
    __syncthreads();
  }
  #undef SAMPLE_CB

  // epilogue: D row = px, col = o
  #pragma unroll
  for (int fo = 0; fo < 2; ++fo) {
    #pragma unroll
    for (int fp = 0; fp < 4; ++fp) {
      const f32x4 a = acc[fo][fp];
      const int o = oS + fo * 16 + ln;
      const int j0 = fp * 16 + (l >> 4) * 4;
      const size_t base = (((size_t)b * CH + o) * HW + i) * HW + j0;
      const float4 xv = *(const float4*)&x[base];
      float4 r; r.x = a[0] + xv.x; r.y = a[1] + xv.y; r.z = a[2] + xv.z; r.w = a[3] + xv.w;
      *(float4*)&out[base] = r;
    }
  }
}

// ---------------------------------------------------------------------------
extern "C" void kernel_launch(void* const* d_in, const int* in_sizes, int n_in,
                              void* d_out, int out_size, void* d_ws, size_t ws_size,
                              hipStream_t stream) {
  (void)in_sizes; (void)n_in; (void)out_size; (void)ws_size;
  const float* x  = (const float*)d_in[0];
  const float* w1 = (const float*)d_in[1];
  const float* b1 = (const float*)d_in[2];
  const float* w2 = (const float*)d_in[3];
  const float* b2 = (const float*)d_in[4];
  const float* pw = (const float*)d_in[5];
  const float* pb = (const float*)d_in[6];
  const float* dw = (const float*)d_in[7];
  float* out = (float*)d_out;

  char* w = (char*)d_ws;
  size_t off = 0;
  auto carve = [&](size_t bytes) { char* p = w + off; off += (bytes + 255) & ~(size_t)255; return p; };
  ushort* xpad  = (ushort*)carve(8929280);
  ushort* res1  = (ushort*)carve(8929280);
  ushort* res2  = (ushort*)carve(8929280);
  ushort* wpk1  = (ushort*)carve(1179648);
  ushort* wpk2  = (ushort*)carve(1179648);
  ushort* wpkO  = (ushort*)carve(147456);
  ushort* dwpk  = (ushort*)carve(1179648);
  float*  pbias = (float*) carve(256);
  float*  offs  = (float*) carve(2097152);

  prep_k<<<1168, 256, 0, stream>>>(x, w1, w2, dw, pw, pb,
                                   xpad, res1, res2, wpk1, wpk2, dwpk, wpkO, pbias);
  conv_mfma<256, 0><<<512, 256, 0, stream>>>(xpad, wpk1, b1, x, res1);
  conv_mfma<256, 1><<<512, 256, 0, stream>>>(res1, wpk2, b2, nullptr, res2);
  conv_mfma<32, 2><<<256, 256, 0, stream>>>(res2, wpkO, pbias, nullptr, offs);
  deform_mfma<<<NB * HW, 512, 0, stream>>>(res2, offs, dwpk, x, out);
}